// Round 12
// baseline (411.692 us; speedup 1.0000x reference)
//
#include <hip/hip_runtime.h>
#include <math.h>

#define BB 32
#define KK 64
#define HH 96
#define WW 128
#define HW (HH*WW)             // 12288
#define MAP_SIZE (BB*KK*HW)    // 25165824
#define NBK (BB*KK)            // 2048
#define NT  (HW/256)           // 48 pixel-tiles per image
#define NBLK (BB*NT)           // 1536 blocks
#define SST 259                // LDS row stride (floats): <=3-way banks everywhere

// ---------------- Fused kernel: softmax + map + reductions + (last block) keypoints --
// Body = round-7 verbatim (best measured: plain loads, NT stores, LDS-staged fp32
// transposed reduce, fp64 atomics). NEW: the 1-block keypoint_k kernel is folded
// into the LAST fused block (atomic-counter last-block idiom), removing one
// dispatch and its GPU-idle launch gap. Cross-XCD safety: producers fence
// (__threadfence) before the device-scope counter RMW; the last block reads sxyz
// with AGENT-scope atomic loads (coherent point), per the m20-verified idiom.
__global__ __launch_bounds__(256, 2) void fused_k(const float* __restrict__ x,
                                                  float* __restrict__ out,
                                                  double* __restrict__ sxyz,
                                                  unsigned int* __restrict__ cnt,
                                                  float* __restrict__ kp,
                                                  float* __restrict__ zeta) {
    __shared__ float sm[KK][SST];   // exp, then normalized values

    int blk  = blockIdx.x;
    int b    = blk / NT;
    int tile = blk - b * NT;
    int t    = threadIdx.x;
    size_t base = (size_t)b * (KK * HW) + (size_t)tile * 256 + t;

    // Phase 1: 64 strided channel loads (PLAIN, coalesced), exp -> LDS, denominator
    // in the same serial k-order as every passing round (bit-identical).
    float den = 0.f;
    #pragma unroll
    for (int k = 0; k < KK; ++k) {
        float e = __expf(x[base + (size_t)k * HW]);
        sm[k][t] = e;
        den += e;
    }
    float inv = 1.f / den;

    // Phase 2: normalize own column; NT-store the map (streaming, nothing re-reads
    // it); stage normalized value for the phase-3 transpose.
    #pragma unroll
    for (int k = 0; k < KK; ++k) {
        float m = sm[k][t] * inv;
        __builtin_nontemporal_store(m, &out[base + (size_t)k * HW]);
        sm[k][t] = m;
    }
    __syncthreads();

    // Phase 3: transposed reduction from LDS, fp32 (r6/r7-verified math/order).
    // Thread (k = t>>2, q = t&3) reduces 64 px of channel k.
    int k = t >> 2;
    int q = t & 3;
    const float gy_base = (float)(tile * 2);
    float z = 0.f, sx = 0.f, sy = 0.f;
    #pragma unroll
    for (int j = 0; j < 16; ++j) {
        int p0 = q * 4 + j * 16;                // p0..p0+3 share a row (no wrap)
        float m0 = sm[k][p0 + 0];
        float m1 = sm[k][p0 + 1];
        float m2 = sm[k][p0 + 2];
        float m3 = sm[k][p0 + 3];
        float s = (m0 + m1) + (m2 + m3);
        z  += s;
        sx += fmaf(s, (float)(p0 & (WW - 1)), fmaf(3.f, m3, fmaf(2.f, m2, m1)));
        sy += s * (gy_base + (float)(p0 >> 7));
    }

    z  += __shfl_xor(z,  1, 64);  z  += __shfl_xor(z,  2, 64);
    sx += __shfl_xor(sx, 1, 64);  sx += __shfl_xor(sx, 2, 64);
    sy += __shfl_xor(sy, 1, 64);  sy += __shfl_xor(sy, 2, 64);
    if (q == 0) {
        int bk = b * KK + k;
        atomicAdd(&sxyz[bk * 3 + 0], (double)sx);
        atomicAdd(&sxyz[bk * 3 + 1], (double)sy);
        atomicAdd(&sxyz[bk * 3 + 2], (double)z);
    }

    // ---- Last-block keypoint fold ----------------------------------------------
    __threadfence();               // producers: sxyz atomics visible device-wide
    __syncthreads();               // block-wide: all atomics issued+fenced
    __shared__ unsigned int sdone;
    if (t == 0) sdone = (atomicAdd(cnt, 1u) == NBLK - 1) ? 1u : 0u;
    __syncthreads();
    if (!sdone) return;

    // This is the last block: all 6144 sxyz entries are final. Inclusive fp64 scan
    // over flattened (b,k) — identical math to the former keypoint_k kernel.
    {
        const int PT = NBK / 256;   // 8
        int lane = t & 63, wid = t >> 6;

        double vx[PT], vy[PT], vz[PT];
        double cx = 0.0, cy = 0.0;
        #pragma unroll
        for (int e = 0; e < PT; ++e) {
            int idx = t * PT + e;
            cx += __hip_atomic_load(&sxyz[idx * 3 + 0], __ATOMIC_RELAXED,
                                    __HIP_MEMORY_SCOPE_AGENT);
            vx[e] = cx;
            cy += __hip_atomic_load(&sxyz[idx * 3 + 1], __ATOMIC_RELAXED,
                                    __HIP_MEMORY_SCOPE_AGENT);
            vy[e] = cy;
            vz[e] = __hip_atomic_load(&sxyz[idx * 3 + 2], __ATOMIC_RELAXED,
                                      __HIP_MEMORY_SCOPE_AGENT);
        }
        double tx = cx, ty = cy;
        for (int off = 1; off < 64; off <<= 1) {
            double ax = __shfl_up(tx, off, 64);
            double ay = __shfl_up(ty, off, 64);
            if (lane >= off) { tx += ax; ty += ay; }
        }
        __shared__ double wxs[4], wys[4];
        if (lane == 63) { wxs[wid] = tx; wys[wid] = ty; }
        __syncthreads();
        double offx = tx - cx, offy = ty - cy;
        for (int w2 = 0; w2 < wid; ++w2) { offx += wxs[w2]; offy += wys[w2]; }

        #pragma unroll
        for (int e = 0; e < PT; ++e) {
            int idx = t * PT + e;
            double zz = vz[e];
            double kx = rint((vx[e] + offx) / zz);
            double ky = rint((vy[e] + offy) / zz);
            float fkx = (float)kx, fky = (float)ky;
            if (fkx > 128.0f || fkx < 0.0f) fkx = 64.0f;   // PRE_WIDTH clamp -> center
            if (fky > 96.0f  || fky < 0.0f) fky = 48.0f;   // PRE_HEIGHT clamp -> center
            kp[idx * 2 + 0] = fkx;
            kp[idx * 2 + 1] = fky;
            zeta[idx] = (float)zz;
        }
    }
}

extern "C" void kernel_launch(void* const* d_in, const int* in_sizes, int n_in,
                              void* d_out, int out_size, void* d_ws, size_t ws_size,
                              hipStream_t stream) {
    const float* x = (const float*)d_in[0];
    float* out  = (float*)d_out;
    float* map  = out;                         // [B,K,H,W]
    float* kp   = out + MAP_SIZE;              // [B,K,2]
    float* zeta = out + MAP_SIZE + NBK * 2;    // [B,K]
    double* sxyz = (double*)d_ws;              // [NBK][3] fp64 accumulators (48 KB)
    unsigned int* cnt = (unsigned int*)((char*)d_ws + NBK * 3 * sizeof(double));

    // Zero accumulators AND the last-block counter (graph replay safe).
    hipMemsetAsync(d_ws, 0, (size_t)NBK * 3 * sizeof(double) + 64, stream);
    fused_k<<< NBLK, 256, 0, stream >>> (x, map, sxyz, cnt, kp, zeta);
}

// Round 13
// 186.931 us; speedup vs baseline: 2.2024x; 2.2024x over previous
//
#include <hip/hip_runtime.h>
#include <math.h>

#define BB 32
#define KK 64
#define HH 96
#define WW 128
#define HW (HH*WW)             // 12288
#define MAP_SIZE (BB*KK*HW)    // 25165824
#define NBK (BB*KK)            // 2048
#define NT  (HW/256)           // 48 pixel-tiles per image
#define SST 259                // LDS row stride (floats): odd-ish -> <=2-3 way banks everywhere

// ---------------- Fused kernel: softmax + map write + per-(b,k) reductions ----------
// SESSION-BEST structure (round 7, 185.7 us), restored verbatim after the r12
// last-block-fold regression (device-scope fence after NT stores = per-block HBM
// write drain, 5x slowdown).
//   - x loads PLAIN        (streamed reads get normal L2/LLC sector handling)
//   - map stores NT        (pure streaming write; nothing ever re-reads the map:
//                           phase 3 reduces from the LDS stage, not from global)
//   - LDS-staged fp32 transposed reduce (r6-verified math), fp64 atomics.
__global__ __launch_bounds__(256, 2) void fused_k(const float* __restrict__ x,
                                                  float* __restrict__ out,
                                                  double* __restrict__ sxyz) {
    __shared__ float sm[KK][SST];   // exp, then normalized values

    int blk  = blockIdx.x;
    int b    = blk / NT;
    int tile = blk - b * NT;
    int t    = threadIdx.x;
    size_t base = (size_t)b * (KK * HW) + (size_t)tile * 256 + t;

    // Phase 1: 64 strided channel loads (PLAIN, coalesced 256 B/instr), exp -> LDS,
    // denominator in the same serial k-order as every passing round (bit-identical).
    // LDS write bank = (3k + t) & 31 over 64 lanes -> 2-way, free.
    float den = 0.f;
    #pragma unroll
    for (int k = 0; k < KK; ++k) {
        float e = __expf(x[base + (size_t)k * HW]);
        sm[k][t] = e;
        den += e;
    }
    float inv = 1.f / den;

    // Phase 2: normalize own column; NT-store the map (streaming, no L2 allocate);
    // write normalized value back to LDS for the phase-3 transpose.
    #pragma unroll
    for (int k = 0; k < KK; ++k) {
        float m = sm[k][t] * inv;
        __builtin_nontemporal_store(m, &out[base + (size_t)k * HW]);
        sm[k][t] = m;
    }
    __syncthreads();   // all columns staged

    // Phase 3: transposed reduction from LDS, fp32 (round-6-verified math, identical
    // summation order). Thread (k = t>>2, q = t&3) reduces 64 px of channel k.
    // Read bank = (3k + 4q + 16j + c) & 31 -> <=3-way across the wave, ~free.
    int k = t >> 2;
    int q = t & 3;
    const float gy_base = (float)(tile * 2);
    float z = 0.f, sx = 0.f, sy = 0.f;
    #pragma unroll
    for (int j = 0; j < 16; ++j) {
        int p0 = q * 4 + j * 16;                // p0..p0+3 share a row (no wrap)
        float m0 = sm[k][p0 + 0];
        float m1 = sm[k][p0 + 1];
        float m2 = sm[k][p0 + 2];
        float m3 = sm[k][p0 + 3];
        float s = (m0 + m1) + (m2 + m3);
        z  += s;
        sx += fmaf(s, (float)(p0 & (WW - 1)), fmaf(3.f, m3, fmaf(2.f, m2, m1)));
        sy += s * (gy_base + (float)(p0 >> 7));
    }

    // Combine the 4 lanes of each channel (lanes differ in bits 0-1 of lane id).
    z  += __shfl_xor(z,  1, 64);  z  += __shfl_xor(z,  2, 64);
    sx += __shfl_xor(sx, 1, 64);  sx += __shfl_xor(sx, 2, 64);
    sy += __shfl_xor(sy, 1, 64);  sy += __shfl_xor(sy, 2, 64);
    if (q == 0) {
        int bk = b * KK + k;
        atomicAdd(&sxyz[bk * 3 + 0], (double)sx);
        atomicAdd(&sxyz[bk * 3 + 1], (double)sy);
        atomicAdd(&sxyz[bk * 3 + 2], (double)z);
    }
}

// ---------------- Keypoints: inclusive fp64 scan over flattened (b,k) ----------------
__global__ __launch_bounds__(256) void keypoint_k(const double* __restrict__ sxyz,
                                                  float* __restrict__ kp,
                                                  float* __restrict__ zeta) {
    const int PT = NBK / 256;   // 8
    int t = threadIdx.x;
    int lane = t & 63, wid = t >> 6;

    double vx[PT], vy[PT], vz[PT];
    double cx = 0.0, cy = 0.0;
    #pragma unroll
    for (int e = 0; e < PT; ++e) {
        int idx = t * PT + e;
        cx += sxyz[idx * 3 + 0]; vx[e] = cx;
        cy += sxyz[idx * 3 + 1]; vy[e] = cy;
        vz[e] = sxyz[idx * 3 + 2];
    }
    double tx = cx, ty = cy;
    for (int off = 1; off < 64; off <<= 1) {
        double ax = __shfl_up(tx, off, 64);
        double ay = __shfl_up(ty, off, 64);
        if (lane >= off) { tx += ax; ty += ay; }
    }
    __shared__ double wxs[4], wys[4];
    if (lane == 63) { wxs[wid] = tx; wys[wid] = ty; }
    __syncthreads();
    double offx = tx - cx, offy = ty - cy;
    for (int w2 = 0; w2 < wid; ++w2) { offx += wxs[w2]; offy += wys[w2]; }

    #pragma unroll
    for (int e = 0; e < PT; ++e) {
        int idx = t * PT + e;
        double zz = vz[e];
        double kx = rint((vx[e] + offx) / zz);
        double ky = rint((vy[e] + offy) / zz);
        float fkx = (float)kx, fky = (float)ky;
        if (fkx > 128.0f || fkx < 0.0f) fkx = 64.0f;   // PRE_WIDTH clamp -> center
        if (fky > 96.0f  || fky < 0.0f) fky = 48.0f;   // PRE_HEIGHT clamp -> center
        kp[idx * 2 + 0] = fkx;
        kp[idx * 2 + 1] = fky;
        zeta[idx] = (float)zz;
    }
}

extern "C" void kernel_launch(void* const* d_in, const int* in_sizes, int n_in,
                              void* d_out, int out_size, void* d_ws, size_t ws_size,
                              hipStream_t stream) {
    const float* x = (const float*)d_in[0];
    float* out  = (float*)d_out;
    float* map  = out;                         // [B,K,H,W]
    float* kp   = out + MAP_SIZE;              // [B,K,2]
    float* zeta = out + MAP_SIZE + NBK * 2;    // [B,K]
    double* sxyz = (double*)d_ws;              // [NBK][3] fp64 accumulators

    hipMemsetAsync(d_ws, 0, (size_t)NBK * 3 * sizeof(double), stream);
    fused_k   <<< BB * NT, 256, 0, stream >>> (x, map, sxyz);
    keypoint_k<<< 1,       256, 0, stream >>> (sxyz, kp, zeta);
}